// Round 1
// baseline (433.615 us; speedup 1.0000x reference)
//
#include <hip/hip_runtime.h>

// out[b] = W[b] - (W[b]@x[b] + eta*gL[b]) * x[b]^T
// B=64, D=1024, fp32. Memory-bound: 256 MiB read (W) + 256 MiB write (out).
//
// Structure: ONE WAVE PER ROW, 4 rows per wave, no LDS, no __syncthreads.
//   - lane l covers cols 4*(l + 64k), k=0..3  -> every load/store instruction
//     is 64 consecutive float4s = 1 KiB, perfectly coalesced.
//   - W tile stays in registers between the dot-product and the rank-1 update,
//     so W is read from HBM exactly once.
//   - reduction = 6-step __shfl_xor butterfly (all lanes get the sum; no
//     broadcast, no barrier, no thread-0 serialization).
//   - gL loads issued at kernel top (wave-uniform -> scalar loads), overlapped
//     with the 16 in-flight W loads instead of sitting between two barriers.
// Block = 256 threads = 4 independent waves = 16 rows. Grid = 65536/16 = 4096.

#define ETA 0.01f

__global__ __launch_bounds__(256) void internal_opt_kernel(
    const float* __restrict__ W,
    const float* __restrict__ x,
    const float* __restrict__ gL,
    float* __restrict__ out)
{
    const int lane = threadIdx.x & 63;
    const int wid  = (blockIdx.x << 2) + (threadIdx.x >> 6);  // global wave id
    const int row0 = wid << 2;                                // 4 rows per wave
    const int b    = row0 >> 10;                              // 4 rows never straddle b (1024 % 4 == 0)

    // gL for this wave's 4 rows: wave-uniform addresses, issue early so the
    // latency hides under the W loads.
    float g[4];
    #pragma unroll
    for (int r = 0; r < 4; ++r) g[r] = gL[row0 + r];

    // x fragments (shared by all 4 rows — same batch b)
    const float* xb = x + (b << 10);
    float4 xf[4];
    #pragma unroll
    for (int k = 0; k < 4; ++k)
        xf[k] = *(const float4*)(xb + ((lane + (k << 6)) << 2));

    // 16 independent coalesced W loads, all issued before any dependent use
    float4 w[4][4];
    #pragma unroll
    for (int r = 0; r < 4; ++r) {
        const float* Wr = W + ((long long)(row0 + r) << 10);
        #pragma unroll
        for (int k = 0; k < 4; ++k)
            w[r][k] = *(const float4*)(Wr + ((lane + (k << 6)) << 2));
    }

    // per-lane partial dot products (16 elements each)
    float p[4];
    #pragma unroll
    for (int r = 0; r < 4; ++r) {
        float a = 0.f;
        #pragma unroll
        for (int k = 0; k < 4; ++k)
            a += w[r][k].x * xf[k].x + w[r][k].y * xf[k].y
               + w[r][k].z * xf[k].z + w[r][k].w * xf[k].w;
        p[r] = a;
    }

    // butterfly reduce across the 64 lanes; 4 independent chains pipeline
    // through the DS unit instead of one latency-bound chain.
    #pragma unroll
    for (int off = 32; off > 0; off >>= 1) {
        #pragma unroll
        for (int r = 0; r < 4; ++r)
            p[r] += __shfl_xor(p[r], off, 64);
    }

    // rank-1 update and store; W never leaves registers
    #pragma unroll
    for (int r = 0; r < 4; ++r) {
        const float s = p[r] + ETA * g[r];
        float* Or = out + ((long long)(row0 + r) << 10);
        #pragma unroll
        for (int k = 0; k < 4; ++k) {
            float4 o;
            o.x = w[r][k].x - s * xf[k].x;
            o.y = w[r][k].y - s * xf[k].y;
            o.z = w[r][k].z - s * xf[k].z;
            o.w = w[r][k].w - s * xf[k].w;
            *(float4*)(Or + ((lane + (k << 6)) << 2)) = o;
        }
    }
}

extern "C" void kernel_launch(void* const* d_in, const int* in_sizes, int n_in,
                              void* d_out, int out_size, void* d_ws, size_t ws_size,
                              hipStream_t stream)
{
    const float* W  = (const float*)d_in[0];
    const float* x  = (const float*)d_in[1];
    const float* gL = (const float*)d_in[2];
    float* out = (float*)d_out;

    const int B = 64, D = 1024;
    // 4 waves/block x 4 rows/wave = 16 rows/block
    dim3 grid((B * D) / 16);
    dim3 block(256);
    internal_opt_kernel<<<grid, block, 0, stream>>>(W, x, gL, out);
}

// Round 3
// 413.590 us; speedup vs baseline: 1.0484x; 1.0484x over previous
//
#include <hip/hip_runtime.h>

// out[b] = W[b] - (W[b]@x[b] + eta*gL[b]) * x[b]^T
// B=64, D=1024, fp32. Memory-bound: 256 MiB read (W) + 256 MiB write (out)
// = 537 MB mandatory HBM traffic -> ~84 us kernel floor at 6.4 TB/s.
//
// Shape (proven fastest in round 0): one 256-thread block per row of W,
// one float4 per thread. Tiny VGPR footprint -> full 8 waves/SIMD occupancy;
// for a pure streaming kernel TLP > ILP (round 1's 4-rows-per-wave ILP
// variant cost ~half the occupancy and ran ~20 us slower end-to-end).
//
// Cleanups vs round 0:
//   - __shfl_xor butterfly: every lane ends with its wave's sum -> only ONE
//     __syncthreads, no thread-0-only serialized gL load between barriers.
//   - gL[row] is block-uniform, issued at kernel top (scalar load, hides
//     under the W vmcnt wait).
//   - nontemporal W load / out store (via native clang vector type — the
//     builtin rejects HIP_vector_type): zero-reuse streams get nt cache
//     policy so the hot x[b] lines (256 KiB, reused by 1024 blocks) stay hot.

#define ETA 0.01f

typedef float floatx4 __attribute__((ext_vector_type(4)));

__global__ __launch_bounds__(256) void internal_opt_kernel(
    const float* __restrict__ W,
    const float* __restrict__ x,
    const float* __restrict__ gL,
    float* __restrict__ out)
{
    const int row = blockIdx.x;          // 0 .. B*D-1  (b = row>>10)
    const int b   = row >> 10;
    const int t   = threadIdx.x;         // thread covers cols 4t..4t+3

    // block-uniform gradient element; issue first so its latency hides
    // under the W load below
    const float g = gL[row];

    const long long woff = ((long long)row << 10) + (t << 2);
    const floatx4 w4 = __builtin_nontemporal_load((const floatx4*)(W + woff));
    const floatx4 x4 = *(const floatx4*)(x + (long long)(b << 10) + (t << 2));

    // partial dot product for (W x)_row
    float p = w4.x * x4.x + w4.y * x4.y + w4.z * x4.z + w4.w * x4.w;

    // wave64 butterfly: all lanes end with the wave sum
    #pragma unroll
    for (int off = 32; off > 0; off >>= 1)
        p += __shfl_xor(p, off, 64);

    __shared__ float wave_sum[4];
    const int wave = t >> 6;
    if ((t & 63) == 0) wave_sum[wave] = p;
    __syncthreads();

    const float s = (wave_sum[0] + wave_sum[1] + wave_sum[2] + wave_sum[3])
                  + ETA * g;

    floatx4 o4;
    o4.x = w4.x - s * x4.x;
    o4.y = w4.y - s * x4.y;
    o4.z = w4.z - s * x4.z;
    o4.w = w4.w - s * x4.w;
    __builtin_nontemporal_store(o4, (floatx4*)(out + woff));
}

extern "C" void kernel_launch(void* const* d_in, const int* in_sizes, int n_in,
                              void* d_out, int out_size, void* d_ws, size_t ws_size,
                              hipStream_t stream)
{
    const float* W  = (const float*)d_in[0];
    const float* x  = (const float*)d_in[1];
    const float* gL = (const float*)d_in[2];
    float* out = (float*)d_out;

    const int B = 64, D = 1024;
    dim3 grid(B * D);   // one block per row
    dim3 block(256);
    internal_opt_kernel<<<grid, block, 0, stream>>>(W, x, gL, out);
}